// Round 1
// baseline (432.484 us; speedup 1.0000x reference)
//
#include <hip/hip_runtime.h>
#include <stdint.h>

#define B_ 4
#define N_ 16384
#define D_ 1024
#define RANK_ 16
#define NUMQ_ 8
#define KSEL_ 1638

// ---------------- Kernel 1: Wq = queries @ Wk  -> [NUMQ, D] ----------------
__global__ __launch_bounds__(256) void wq_kernel(const float* __restrict__ Wk,
                                                 const float* __restrict__ queries,
                                                 float* __restrict__ Wq) {
    int i = blockIdx.x * 256 + threadIdx.x;   // 0 .. NUMQ*D-1 (8192)
    if (i >= NUMQ_ * D_) return;
    int q = i >> 10;          // / D_
    int d = i & (D_ - 1);     // % D_
    float acc = 0.f;
#pragma unroll
    for (int r = 0; r < RANK_; ++r)
        acc += queries[q * RANK_ + r] * Wk[r * D_ + d];
    Wq[i] = acc;
}

// ------------- Kernel 2: token_scores[t] = max_q ( x[t,:] . Wq[q,:] ) -------------
// One wave processes TOK=4 tokens per iteration. Wq staged in LDS (32 KiB).
#define TOK 4
__global__ __launch_bounds__(256) void score_kernel(const float* __restrict__ x,
                                                    const float* __restrict__ Wq,
                                                    float* __restrict__ scores) {
    __shared__ float sWq[NUMQ_ * D_];   // 32 KiB
    for (int i = threadIdx.x; i < NUMQ_ * D_; i += 256)
        sWq[i] = Wq[i];
    __syncthreads();

    const int lane = threadIdx.x & 63;
    const int wave = threadIdx.x >> 6;
    const int gw = blockIdx.x * 4 + wave;
    const int numWaves = gridDim.x * 4;
    const int totalTok = B_ * N_;

    for (int t0 = gw * TOK; t0 < totalTok; t0 += numWaves * TOK) {
        float acc[TOK][NUMQ_];
#pragma unroll
        for (int t = 0; t < TOK; ++t)
#pragma unroll
            for (int q = 0; q < NUMQ_; ++q) acc[t][q] = 0.f;

#pragma unroll
        for (int j = 0; j < 4; ++j) {
            const int off = j * 256 + lane * 4;   // lane-coalesced float4
            float4 xv[TOK];
#pragma unroll
            for (int t = 0; t < TOK; ++t)
                xv[t] = *(const float4*)(x + (size_t)(t0 + t) * D_ + off);
#pragma unroll
            for (int q = 0; q < NUMQ_; ++q) {
                float4 w = *(const float4*)(sWq + q * D_ + off);
#pragma unroll
                for (int t = 0; t < TOK; ++t) {
                    acc[t][q] += xv[t].x * w.x;
                    acc[t][q] += xv[t].y * w.y;
                    acc[t][q] += xv[t].z * w.z;
                    acc[t][q] += xv[t].w * w.w;
                }
            }
        }

        // cross-lane sum per (token, q), then max over q
#pragma unroll
        for (int t = 0; t < TOK; ++t) {
            float m = -3.0e38f;
#pragma unroll
            for (int q = 0; q < NUMQ_; ++q) {
                float v = acc[t][q];
#pragma unroll
                for (int s = 32; s > 0; s >>= 1)
                    v += __shfl_xor(v, s, 64);
                m = fmaxf(m, v);
            }
            if (lane == 0) scores[t0 + t] = m;
        }
    }
}

// ------------- Kernel 3: per-batch top-K indices, sorted ascending -------------
// Radix-select (4 x 8-bit passes, MSB first) on order-preserving uint32 keys,
// then an ordered compaction that emits indices already sorted, with exact
// smallest-index tie-breaking at the cutoff value (matches top_k semantics).
__global__ __launch_bounds__(256) void topk_kernel(const float* __restrict__ scores,
                                                   int* __restrict__ out) {
    __shared__ uint32_t sKeys[N_];        // 64 KiB
    __shared__ uint32_t hist[256];
    __shared__ uint32_t sGT[256];
    __shared__ uint32_t sEQ[256];
    __shared__ uint32_t sPrefix, sR;

    const int b = blockIdx.x;
    const int tid = threadIdx.x;
    const float* s = scores + b * N_;

    // load + order-preserving transform (larger float -> larger uint)
    for (int i = tid; i < N_; i += 256) {
        uint32_t u = __float_as_uint(s[i]);
        u = (u & 0x80000000u) ? ~u : (u | 0x80000000u);
        sKeys[i] = u;
    }
    __syncthreads();

    uint32_t prefix = 0;
    uint32_t R = KSEL_;   // rank (from the top) we are hunting within current prefix class

    for (int shift = 24; shift >= 0; shift -= 8) {
        hist[tid] = 0;
        __syncthreads();
        const uint32_t maskHi = (shift == 24) ? 0u : (0xFFFFFFFFu << (shift + 8));
        for (int i = tid; i < N_; i += 256) {
            uint32_t u = sKeys[i];
            if ((u & maskHi) == prefix)
                atomicAdd(&hist[(u >> shift) & 255u], 1u);
        }
        __syncthreads();
        if (tid == 0) {
            uint32_t cum = 0;   // count strictly above selected bin
            int sel = 0;
            for (int bin = 255; bin >= 0; --bin) {
                uint32_t c = hist[bin];
                if (cum + c >= R) { sel = bin; break; }
                cum += c;
            }
            sPrefix = prefix | ((uint32_t)sel << shift);
            sR = R - cum;
        }
        __syncthreads();
        prefix = sPrefix;
        R = sR;
        __syncthreads();
    }

    const uint32_t T = prefix;  // exact Kth-largest key
    const uint32_t need = R;    // how many ==T to take (smallest indices first)

    // per-thread counts over a contiguous chunk of 64 elements
    const int CHUNK = N_ / 256; // 64
    const int base = tid * CHUNK;
    uint32_t cGT = 0, cEQ = 0;
    for (int i = 0; i < CHUNK; ++i) {
        uint32_t u = sKeys[base + i];
        cGT += (u > T);
        cEQ += (u == T);
    }
    sGT[tid] = cGT;
    sEQ[tid] = cEQ;
    __syncthreads();
    if (tid == 0) {
        uint32_t aG = 0, aE = 0;
        for (int i = 0; i < 256; ++i) {
            uint32_t g = sGT[i], e = sEQ[i];
            sGT[i] = aG; sEQ[i] = aE;
            aG += g; aE += e;
        }
    }
    __syncthreads();

    uint32_t gt = sGT[tid];   // # of >T elements before my chunk
    uint32_t eq = sEQ[tid];   // # of ==T elements before my chunk
    int* ob = out + b * KSEL_;
    for (int i = 0; i < CHUNK; ++i) {
        uint32_t u = sKeys[base + i];
        if (u > T) {
            uint32_t eqSel = (eq < need) ? eq : need;
            ob[gt + eqSel] = base + i;
            gt++;
        } else if (u == T) {
            if (eq < need) ob[gt + eq] = base + i;
            eq++;
        }
    }
}

extern "C" void kernel_launch(void* const* d_in, const int* in_sizes, int n_in,
                              void* d_out, int out_size, void* d_ws, size_t ws_size,
                              hipStream_t stream) {
    const float* x       = (const float*)d_in[0];   // [B, N, D]
    const float* Wk      = (const float*)d_in[1];   // [RANK, D]
    const float* queries = (const float*)d_in[2];   // [NUMQ, RANK]
    int* out = (int*)d_out;                         // [B, KSEL] int32

    float* Wq     = (float*)d_ws;                               // 32 KiB
    float* scores = (float*)((char*)d_ws + NUMQ_ * D_ * sizeof(float)); // 256 KiB

    wq_kernel<<<(NUMQ_ * D_ + 255) / 256, 256, 0, stream>>>(Wk, queries, Wq);
    score_kernel<<<2048, 256, 0, stream>>>(x, Wq, scores);
    topk_kernel<<<B_, 256, 0, stream>>>(scores, out);
}

// Round 2
// 410.460 us; speedup vs baseline: 1.0537x; 1.0537x over previous
//
#include <hip/hip_runtime.h>
#include <stdint.h>

#define B_ 4
#define N_ 16384
#define D_ 1024
#define RANK_ 16
#define NUMQ_ 8
#define KSEL_ 1638

// ---------------- Kernel 1: Wq = queries @ Wk  -> [NUMQ, D] ----------------
__global__ __launch_bounds__(256) void wq_kernel(const float* __restrict__ Wk,
                                                 const float* __restrict__ queries,
                                                 float* __restrict__ Wq) {
    int i = blockIdx.x * 256 + threadIdx.x;   // 0 .. NUMQ*D-1 (8192)
    if (i >= NUMQ_ * D_) return;
    int q = i >> 10;          // / D_
    int d = i & (D_ - 1);     // % D_
    float acc = 0.f;
#pragma unroll
    for (int r = 0; r < RANK_; ++r)
        acc += queries[q * RANK_ + r] * Wk[r * D_ + d];
    Wq[i] = acc;
}

// ------------- Kernel 2: token_scores[t] = max_q ( x[t,:] . Wq[q,:] ) -------------
// One wave processes TOK=4 tokens per iteration. Wq staged in LDS (32 KiB).
// Reduction: folding multi-value butterfly — 13 shuffles/token instead of 48.
#define TOK 4

// FOLD: keep one of (a,b) per lane-half (by `bit`), exchange the other at
// xor-distance `dist`, and sum. Output value-index mapping: q gains bit*step.
#define FOLD(dst, a, b, bit, dist)                          \
    {                                                       \
        float _send = (bit) ? (a) : (b);                    \
        float _recv = __shfl_xor(_send, (dist), 64);        \
        (dst) = ((bit) ? (b) : (a)) + _recv;                \
    }

__global__ __launch_bounds__(256) void score_kernel(const float* __restrict__ x,
                                                    const float* __restrict__ Wq,
                                                    float* __restrict__ scores) {
    __shared__ float sWq[NUMQ_ * D_];   // 32 KiB
    for (int i = threadIdx.x; i < NUMQ_ * D_; i += 256)
        sWq[i] = Wq[i];
    __syncthreads();

    const int lane = threadIdx.x & 63;
    const int wave = threadIdx.x >> 6;
    const int gw = blockIdx.x * 4 + wave;
    const int numWaves = gridDim.x * 4;
    const int totalTok = B_ * N_;

    const int l5 = (lane >> 5) & 1;
    const int l4 = (lane >> 4) & 1;
    const int l3 = (lane >> 3) & 1;

    for (int t0 = gw * TOK; t0 < totalTok; t0 += numWaves * TOK) {
        float acc[TOK][NUMQ_];
#pragma unroll
        for (int t = 0; t < TOK; ++t)
#pragma unroll
            for (int q = 0; q < NUMQ_; ++q) acc[t][q] = 0.f;

#pragma unroll
        for (int j = 0; j < 4; ++j) {
            const int off = j * 256 + lane * 4;   // lane-coalesced float4
            float4 xv[TOK];
#pragma unroll
            for (int t = 0; t < TOK; ++t)
                xv[t] = *(const float4*)(x + (size_t)(t0 + t) * D_ + off);
#pragma unroll
            for (int q = 0; q < NUMQ_; ++q) {
                float4 w = *(const float4*)(sWq + q * D_ + off);
#pragma unroll
                for (int t = 0; t < TOK; ++t) {
                    acc[t][q] += xv[t].x * w.x;
                    acc[t][q] += xv[t].y * w.y;
                    acc[t][q] += xv[t].z * w.z;
                    acc[t][q] += xv[t].w * w.w;
                }
            }
        }

        // Folding butterfly: 8 dot-sums spread across 8 lane-octants,
        // then butterfly-max over octants. 13 shuffles per token.
#pragma unroll
        for (int t = 0; t < TOK; ++t) {
            float n0, n1, n2, n3;
            FOLD(n0, acc[t][0], acc[t][4], l5, 32)
            FOLD(n1, acc[t][1], acc[t][5], l5, 32)
            FOLD(n2, acc[t][2], acc[t][6], l5, 32)
            FOLD(n3, acc[t][3], acc[t][7], l5, 32)
            float m0, m1;
            FOLD(m0, n0, n2, l4, 16)
            FOLD(m1, n1, n3, l4, 16)
            float p;
            FOLD(p, m0, m1, l3, 8)
            p += __shfl_xor(p, 4, 64);
            p += __shfl_xor(p, 2, 64);
            p += __shfl_xor(p, 1, 64);
            // p = full dot for q = 4*l5 + 2*l4 + l3 (replicated on 8 lanes)
            float mx = p;
            mx = fmaxf(mx, __shfl_xor(mx, 8, 64));
            mx = fmaxf(mx, __shfl_xor(mx, 16, 64));
            mx = fmaxf(mx, __shfl_xor(mx, 32, 64));
            if (lane == 0) scores[t0 + t] = mx;
        }
    }
}

// ------------- Kernel 3: per-batch top-K indices, sorted ascending -------------
// Radix-select with 11/11/10-bit passes (2048-bin histogram) so the hot
// exponent buckets of the score distribution are spread over mantissa bits
// (kills LDS same-address atomic serialization). Hierarchical (256-segment)
// top-down scan replaces the serial 256-bin walk. Ordered compaction emits
// indices already sorted ascending with exact smallest-index tie-breaking.
__global__ __launch_bounds__(256) void topk_kernel(const float* __restrict__ scores,
                                                   int* __restrict__ out) {
    __shared__ uint32_t sKeys[N_];        // 64 KiB
    __shared__ uint32_t hist[2048];       // 8 KiB
    __shared__ uint32_t segSum[256];
    __shared__ uint32_t sGT[256];
    __shared__ uint32_t sEQ[256];
    __shared__ uint32_t sPrefix, sR;

    const int b = blockIdx.x;
    const int tid = threadIdx.x;
    const float* s = scores + b * N_;

    // load + order-preserving transform (larger float -> larger uint)
    for (int i = tid; i < N_; i += 256) {
        uint32_t u = __float_as_uint(s[i]);
        u = (u & 0x80000000u) ? ~u : (u | 0x80000000u);
        sKeys[i] = u;
    }
    __syncthreads();

    uint32_t prefix = 0;
    uint32_t R = KSEL_;   // rank from the top within the current prefix class

    const int shifts[3]  = {21, 10, 0};
    const int widths[3]  = {11, 11, 10};

#pragma unroll 1
    for (int pass = 0; pass < 3; ++pass) {
        const int shift = shifts[pass];
        const uint32_t nb = 1u << widths[pass];
        const uint32_t binmask = nb - 1u;
        const uint32_t maskHi = (pass == 0) ? 0u
                              : (0xFFFFFFFFu << (shift + widths[pass]));

        for (int i = tid; i < (int)nb; i += 256) hist[i] = 0;
        __syncthreads();
        for (int i = tid; i < N_; i += 256) {
            uint32_t u = sKeys[i];
            if ((u & maskHi) == prefix)
                atomicAdd(&hist[(u >> shift) & binmask], 1u);
        }
        __syncthreads();

        // segment sums: each thread owns nb/256 consecutive bins
        const int seg = (int)(nb >> 8);
        uint32_t ssum = 0;
        for (int j = 0; j < seg; ++j) ssum += hist[tid * seg + j];
        segSum[tid] = ssum;
        __syncthreads();

        if (tid == 0) {
            uint32_t cum = 0;   // count strictly above the selected bin
            int ts = 0;
            for (int t2 = 255; t2 >= 0; --t2) {
                uint32_t c = segSum[t2];
                if (cum + c >= R) { ts = t2; break; }
                cum += c;
            }
            int sel = ts * seg;
            for (int bin = ts * seg + seg - 1; bin >= ts * seg; --bin) {
                uint32_t c = hist[bin];
                if (cum + c >= R) { sel = bin; break; }
                cum += c;
            }
            sPrefix = prefix | ((uint32_t)sel << shift);
            sR = R - cum;
        }
        __syncthreads();
        prefix = sPrefix;
        R = sR;
        __syncthreads();
    }

    const uint32_t T = prefix;  // exact Kth-largest key
    const uint32_t need = R;    // how many ==T to take (smallest indices first)

    // per-thread counts over a contiguous chunk of 64 elements
    const int CHUNK = N_ / 256; // 64
    const int base = tid * CHUNK;
    uint32_t cGT = 0, cEQ = 0;
    for (int i = 0; i < CHUNK; ++i) {
        uint32_t u = sKeys[base + i];
        cGT += (u > T);
        cEQ += (u == T);
    }
    sGT[tid] = cGT;
    sEQ[tid] = cEQ;
    __syncthreads();
    if (tid == 0) {
        uint32_t aG = 0, aE = 0;
        for (int i = 0; i < 256; ++i) {
            uint32_t g = sGT[i], e = sEQ[i];
            sGT[i] = aG; sEQ[i] = aE;
            aG += g; aE += e;
        }
    }
    __syncthreads();

    uint32_t gt = sGT[tid];   // # of >T elements before my chunk
    uint32_t eq = sEQ[tid];   // # of ==T elements before my chunk
    int* ob = out + b * KSEL_;
    for (int i = 0; i < CHUNK; ++i) {
        uint32_t u = sKeys[base + i];
        if (u > T) {
            uint32_t eqSel = (eq < need) ? eq : need;
            ob[gt + eqSel] = base + i;
            gt++;
        } else if (u == T) {
            if (eq < need) ob[gt + eq] = base + i;
            eq++;
        }
    }
}

extern "C" void kernel_launch(void* const* d_in, const int* in_sizes, int n_in,
                              void* d_out, int out_size, void* d_ws, size_t ws_size,
                              hipStream_t stream) {
    const float* x       = (const float*)d_in[0];   // [B, N, D]
    const float* Wk      = (const float*)d_in[1];   // [RANK, D]
    const float* queries = (const float*)d_in[2];   // [NUMQ, RANK]
    int* out = (int*)d_out;                         // [B, KSEL] int32

    float* Wq     = (float*)d_ws;                               // 32 KiB
    float* scores = (float*)((char*)d_ws + NUMQ_ * D_ * sizeof(float)); // 256 KiB

    wq_kernel<<<(NUMQ_ * D_ + 255) / 256, 256, 0, stream>>>(Wk, queries, Wq);
    score_kernel<<<2048, 256, 0, stream>>>(x, Wq, scores);
    topk_kernel<<<B_, 256, 0, stream>>>(scores, out);
}

// Round 3
// 384.468 us; speedup vs baseline: 1.1249x; 1.0676x over previous
//
#include <hip/hip_runtime.h>
#include <stdint.h>

#define B_ 4
#define N_ 16384
#define D_ 1024
#define RANK_ 16
#define NUMQ_ 8
#define KSEL_ 1638

// ---------------- Kernel 1: Wq = queries @ Wk  -> [NUMQ, D] ----------------
__global__ __launch_bounds__(256) void wq_kernel(const float* __restrict__ Wk,
                                                 const float* __restrict__ queries,
                                                 float* __restrict__ Wq) {
    int i = blockIdx.x * 256 + threadIdx.x;   // 0 .. NUMQ*D-1 (8192)
    if (i >= NUMQ_ * D_) return;
    int q = i >> 10;          // / D_
    int d = i & (D_ - 1);     // % D_
    float acc = 0.f;
#pragma unroll
    for (int r = 0; r < RANK_; ++r)
        acc += queries[q * RANK_ + r] * Wk[r * D_ + d];
    Wq[i] = acc;
}

// ------------- Kernel 2: token_scores[t] = max_q ( x[t,:] . Wq[q,:] ) -------------
// One wave processes TOK=4 tokens per iteration. Wq staged in LDS (32 KiB).
// Reduction: folding multi-value butterfly — 13 shuffles/token.
#define TOK 4

#define FOLD(dst, a, b, bit, dist)                          \
    {                                                       \
        float _send = (bit) ? (a) : (b);                    \
        float _recv = __shfl_xor(_send, (dist), 64);        \
        (dst) = ((bit) ? (b) : (a)) + _recv;                \
    }

__global__ __launch_bounds__(256) void score_kernel(const float* __restrict__ x,
                                                    const float* __restrict__ Wq,
                                                    float* __restrict__ scores) {
    __shared__ float sWq[NUMQ_ * D_];   // 32 KiB
    for (int i = threadIdx.x; i < NUMQ_ * D_; i += 256)
        sWq[i] = Wq[i];
    __syncthreads();

    const int lane = threadIdx.x & 63;
    const int wave = threadIdx.x >> 6;
    const int gw = blockIdx.x * 4 + wave;
    const int numWaves = gridDim.x * 4;
    const int totalTok = B_ * N_;

    const int l5 = (lane >> 5) & 1;
    const int l4 = (lane >> 4) & 1;
    const int l3 = (lane >> 3) & 1;

    for (int t0 = gw * TOK; t0 < totalTok; t0 += numWaves * TOK) {
        float acc[TOK][NUMQ_];
#pragma unroll
        for (int t = 0; t < TOK; ++t)
#pragma unroll
            for (int q = 0; q < NUMQ_; ++q) acc[t][q] = 0.f;

#pragma unroll
        for (int j = 0; j < 4; ++j) {
            const int off = j * 256 + lane * 4;   // lane-coalesced float4
            float4 xv[TOK];
#pragma unroll
            for (int t = 0; t < TOK; ++t)
                xv[t] = *(const float4*)(x + (size_t)(t0 + t) * D_ + off);
#pragma unroll
            for (int q = 0; q < NUMQ_; ++q) {
                float4 w = *(const float4*)(sWq + q * D_ + off);
#pragma unroll
                for (int t = 0; t < TOK; ++t) {
                    acc[t][q] += xv[t].x * w.x;
                    acc[t][q] += xv[t].y * w.y;
                    acc[t][q] += xv[t].z * w.z;
                    acc[t][q] += xv[t].w * w.w;
                }
            }
        }

#pragma unroll
        for (int t = 0; t < TOK; ++t) {
            float n0, n1, n2, n3;
            FOLD(n0, acc[t][0], acc[t][4], l5, 32)
            FOLD(n1, acc[t][1], acc[t][5], l5, 32)
            FOLD(n2, acc[t][2], acc[t][6], l5, 32)
            FOLD(n3, acc[t][3], acc[t][7], l5, 32)
            float m0, m1;
            FOLD(m0, n0, n2, l4, 16)
            FOLD(m1, n1, n3, l4, 16)
            float p;
            FOLD(p, m0, m1, l3, 8)
            p += __shfl_xor(p, 4, 64);
            p += __shfl_xor(p, 2, 64);
            p += __shfl_xor(p, 1, 64);
            float mx = p;
            mx = fmaxf(mx, __shfl_xor(mx, 8, 64));
            mx = fmaxf(mx, __shfl_xor(mx, 16, 64));
            mx = fmaxf(mx, __shfl_xor(mx, 32, 64));
            if (lane == 0) scores[t0 + t] = mx;
        }
    }
}

// ------------- Kernel 3: per-batch top-K indices, sorted ascending -------------
// Radix-select 11/11/10 bits. All formerly-serial scans parallelized:
//  * per-pass bin select: wave suffix-scan (shfl_down) + cross-wave combine,
//    unique-boundary thread picks the target segment; <=4-bin serial tail.
//  * GT/EQ compaction offsets: packed (GT<<16|EQ) wave prefix scan (shfl_up).
// 512 threads/block. Ordered compaction emits indices sorted ascending with
// exact smallest-index tie-breaking at the cutoff (matches top_k semantics).
__global__ __launch_bounds__(512) void topk_kernel(const float* __restrict__ scores,
                                                   int* __restrict__ out) {
    __shared__ uint32_t sKeys[N_];        // 64 KiB
    __shared__ uint32_t hist[2048];       // 8 KiB
    __shared__ uint32_t sSuf[512];        // 2 KiB
    __shared__ uint32_t waveTot[8];
    __shared__ uint32_t wTotG[8];
    __shared__ int sTs;
    __shared__ uint32_t sPrefix, sR;

    const int b = blockIdx.x;
    const int tid = threadIdx.x;
    const int lane = tid & 63;
    const int wave = tid >> 6;
    const float* s = scores + b * N_;

    // load + order-preserving transform (larger float -> larger uint)
    for (int i = tid; i < N_; i += 512) {
        uint32_t u = __float_as_uint(s[i]);
        u = (u & 0x80000000u) ? ~u : (u | 0x80000000u);
        sKeys[i] = u;
    }
    __syncthreads();

    uint32_t prefix = 0;
    uint32_t R = KSEL_;   // rank from the top within the current prefix class

    const int shifts[3] = {21, 10, 0};
    const int widths[3] = {11, 11, 10};

#pragma unroll 1
    for (int pass = 0; pass < 3; ++pass) {
        const int shift = shifts[pass];
        const uint32_t nb = 1u << widths[pass];
        const uint32_t binmask = nb - 1u;
        const uint32_t maskHi = (pass == 0) ? 0u
                              : (0xFFFFFFFFu << (shift + widths[pass]));

        for (int i = tid; i < (int)nb; i += 512) hist[i] = 0;
        __syncthreads();
        for (int i = tid; i < N_; i += 512) {
            uint32_t u = sKeys[i];
            if ((u & maskHi) == prefix)
                atomicAdd(&hist[(u >> shift) & binmask], 1u);
        }
        __syncthreads();

        // per-thread segment sum (seg consecutive bins), then suffix scan
        const int seg = (int)(nb >> 9);            // nb/512: 4,4,2
        uint32_t v = 0;
        for (int j = 0; j < seg; ++j) v += hist[tid * seg + j];

        // wave-level inclusive suffix scan: v = sum over lanes >= lane
#pragma unroll
        for (int d = 1; d < 64; d <<= 1) {
            uint32_t t = __shfl_down(v, (unsigned)d, 64);
            if (lane + d < 64) v += t;
        }
        if (lane == 0) waveTot[wave] = v;          // wave total
        __syncthreads();
        uint32_t basev = 0;
        for (int w = wave + 1; w < 8; ++w) basev += waveTot[w];
        uint32_t suf = v + basev;                  // inclusive suffix over 512
        sSuf[tid] = suf;
        __syncthreads();

        // unique boundary: largest tid with suffix >= R
        if (suf >= R && (tid == 511 || sSuf[tid + 1] < R)) sTs = tid;
        __syncthreads();
        const int ts = sTs;

        if (tid == 0) {
            uint32_t cum = (ts < 511) ? sSuf[ts + 1] : 0u;  // strictly above segment
            int sel = ts * seg;
            for (int bin = ts * seg + seg - 1; bin >= ts * seg; --bin) {
                uint32_t c = hist[bin];
                if (cum + c >= R) { sel = bin; break; }
                cum += c;
            }
            sPrefix = prefix | ((uint32_t)sel << shift);
            sR = R - cum;
        }
        __syncthreads();
        prefix = sPrefix;
        R = sR;
        __syncthreads();
    }

    const uint32_t T = prefix;  // exact Kth-largest key
    const uint32_t need = R;    // how many ==T to take (smallest indices first)

    // per-thread counts over a contiguous chunk, packed (GT<<16 | EQ).
    // Totals: GT < KSEL_=1638, EQ <= 16384 — both fit in 16 bits.
    const int CHUNK = N_ / 512; // 32
    const int base = tid * CHUNK;
    uint32_t cGT = 0, cEQ = 0;
    for (int i = 0; i < CHUNK; ++i) {
        uint32_t u = sKeys[base + i];
        cGT += (u > T);
        cEQ += (u == T);
    }
    uint32_t packed = (cGT << 16) | cEQ;
    uint32_t pv = packed;
#pragma unroll
    for (int d = 1; d < 64; d <<= 1) {
        uint32_t t = __shfl_up(pv, (unsigned)d, 64);
        if (lane >= d) pv += t;
    }
    if (lane == 63) wTotG[wave] = pv;              // wave total
    __syncthreads();
    uint32_t pbase = 0;
    for (int w = 0; w < wave; ++w) pbase += wTotG[w];
    uint32_t excl = pbase + pv - packed;           // exclusive prefix
    uint32_t gt = excl >> 16;
    uint32_t eq = excl & 0xFFFFu;

    int* ob = out + b * KSEL_;
    for (int i = 0; i < CHUNK; ++i) {
        uint32_t u = sKeys[base + i];
        if (u > T) {
            uint32_t eqSel = (eq < need) ? eq : need;
            ob[gt + eqSel] = base + i;
            gt++;
        } else if (u == T) {
            if (eq < need) ob[gt + eq] = base + i;
            eq++;
        }
    }
}

extern "C" void kernel_launch(void* const* d_in, const int* in_sizes, int n_in,
                              void* d_out, int out_size, void* d_ws, size_t ws_size,
                              hipStream_t stream) {
    const float* x       = (const float*)d_in[0];   // [B, N, D]
    const float* Wk      = (const float*)d_in[1];   // [RANK, D]
    const float* queries = (const float*)d_in[2];   // [NUMQ, RANK]
    int* out = (int*)d_out;                         // [B, KSEL] int32

    float* Wq     = (float*)d_ws;                               // 32 KiB
    float* scores = (float*)((char*)d_ws + NUMQ_ * D_ * sizeof(float)); // 256 KiB

    wq_kernel<<<(NUMQ_ * D_ + 255) / 256, 256, 0, stream>>>(Wk, queries, Wq);
    score_kernel<<<2048, 256, 0, stream>>>(x, Wq, scores);
    topk_kernel<<<B_, 512, 0, stream>>>(scores, out);
}